// Round 10
// baseline (288.855 us; speedup 1.0000x reference)
//
#include <hip/hip_runtime.h>

#define S_ 64
#define P_ 2048
#define C_ 32
#define A_ 2048
#define D_ 128
#define E_ 64

#define LPX  128             // pixels per fused block
#define NLCH (P_ / LPX)      // 16 chunks per scene
#define GRP  16              // agents per group (16 -> small LDS, 5 blocks/CU)

// ---------------------------------------------------------------------------
// prep: att2[a,:] = de[a,:] @ W_df + b_df (128 blocks).
// Block 0 additionally: zero Z + scene_done, and a deterministic scan-scatter
// (thread j owns scene j; sequential over sidx in LDS) - no atomics, no memset.
// ---------------------------------------------------------------------------
__global__ __launch_bounds__(256) void prep_kernel(
    const float* __restrict__ de, const float* __restrict__ Wdf,
    const float* __restrict__ bdf, const int* __restrict__ sidx,
    float* __restrict__ att2, int* __restrict__ counts,
    int* __restrict__ lists, float* __restrict__ Z,
    int* __restrict__ scene_done) {
  __shared__ float4 Wl[128 * 16];   // 32 KB
  __shared__ float4 bl[16];
  __shared__ float  dl[16 * 128];   // 8 KB
  __shared__ int    sl[A_];         // 8 KB (block 0 scan only)
  const int tid = threadIdx.x;

  if (blockIdx.x == 0) {
    for (int i = tid; i < A_; i += 256) { Z[i] = 0.f; sl[i] = sidx[i]; }
    if (tid < S_) scene_done[tid] = 0;
    __syncthreads();
    if (tid < S_) {
      int cnt = 0;
      for (int a = 0; a < A_; ++a)
        if (sl[a] == tid) lists[tid * A_ + cnt++] = a;
      counts[tid] = cnt;
    }
  }

  const float4* W4 = (const float4*)Wdf;
#pragma unroll
  for (int i = 0; i < 8; ++i) Wl[tid + i * 256] = W4[tid + i * 256];
  if (tid < 16) bl[tid] = ((const float4*)bdf)[tid];
  const long base = (long)blockIdx.x * (16 * 128);
#pragma unroll
  for (int i = 0; i < 8; ++i) dl[tid + i * 256] = de[base + tid + i * 256];
  __syncthreads();

  const int r = tid >> 4, e4 = tid & 15;
  float4 acc = bl[e4];
#pragma unroll 4
  for (int d = 0; d < 128; ++d) {
    const float  g = dl[r * 128 + d];
    const float4 w = Wl[d * 16 + e4];
    acc.x = fmaf(g, w.x, acc.x);
    acc.y = fmaf(g, w.y, acc.y);
    acc.z = fmaf(g, w.z, acc.z);
    acc.w = fmaf(g, w.w, acc.w);
  }
  ((float4*)att2)[((long)blockIdx.x * 16 + r) * 16 + e4] = acc;
}

// ---------------------------------------------------------------------------
// Fused logits + unnormalized exp + pooling + per-scene last-block normalize.
// Block = (scene, 128-px chunk). Phase 1 lane = (px = tid>>1, eh = tid&1):
// 32 e's per lane; exp needs no max subtraction (|logit| <~ 10, |w_fc|<=1/8).
// Phase 2 lane = (j2 = tid>>4, cp = tid&15): channel PAIR per lane, pool vs
// LDS gs chunk, write per-chunk partials. LDS ~31 KB -> 5 blocks/CU.
// Epilogue: 16th block of a scene (scene_done) reduces partials / Z -> out.
// ---------------------------------------------------------------------------
__global__ __launch_bounds__(256) void fused_kernel(
    const float* __restrict__ gs, const float* __restrict__ Wsn,
    const float* __restrict__ bsn, const float* __restrict__ wfc,
    const float* __restrict__ att2, const int* __restrict__ counts,
    const int* __restrict__ lists, float* __restrict__ partial,
    float* __restrict__ Z, int* __restrict__ scene_done,
    float* __restrict__ out) {
  const int s   = blockIdx.x >> 4;
  const int ch  = blockIdx.x & (NLCH - 1);
  const int p0  = ch * LPX;
  const int tid = threadIdx.x;
  const int px  = tid >> 1;          // 0..127
  const int eh  = tid & 1;           // e-half (32 e's)

  __shared__ float  gsl[LPX][36];    // 18.4 KB; 144 B rows (16B-aligned)
  __shared__ float  ubuf[GRP * 132]; // 8.45 KB: Wl4 (preamble) / alpha_l (loop)
  __shared__ float4 a2l[GRP][16];    // 4 KB
  __shared__ int    aidl[GRP];
  __shared__ int    lastFlag;

  float4* Wl4 = (float4*)ubuf;                       // 512 float4 (8 KB) used
  float (*alpha_l)[132] = (float(*)[132])ubuf;

  // stage W_sn (512 float4)
  const float4* W4 = (const float4*)Wsn;
  Wl4[tid]       = W4[tid];
  Wl4[tid + 256] = W4[tid + 256];

  // stage gs chunk: 128 px x 32 c = 1024 float4
  const float4* g4 = (const float4*)(gs + ((long)s * P_ + p0) * C_);
#pragma unroll
  for (int k = 0; k < 4; ++k) {
    const int f = tid + k * 256;
    const float4 v = g4[f];
    const int pp = f >> 3, c0 = (f & 7) * 4;
    gsl[pp][c0]     = v.x;
    gsl[pp][c0 + 1] = v.y;
    gsl[pp][c0 + 2] = v.z;
    gsl[pp][c0 + 3] = v.w;
  }

  // per-lane w_fc and bias-initialized att1 accumulator (32 e's each)
  const float4* wf4 = (const float4*)wfc;
  const float4* b4  = (const float4*)bsn;
  float4 wf[8], a1[8];
#pragma unroll
  for (int q = 0; q < 8; ++q) { wf[q] = wf4[eh * 8 + q]; a1[q] = b4[eh * 8 + q]; }
  __syncthreads();

  // att1 for (pixel px, this lane's 32 e's): last reads of Wl4 (= ubuf)
#pragma unroll
  for (int c = 0; c < 32; ++c) {
    const float g = gsl[px][c];
#pragma unroll
    for (int q = 0; q < 8; ++q) {
      const float4 w = Wl4[c * 16 + eh * 8 + q];
      a1[q].x = fmaf(g, w.x, a1[q].x);
      a1[q].y = fmaf(g, w.y, a1[q].y);
      a1[q].z = fmaf(g, w.z, a1[q].z);
      a1[q].w = fmaf(g, w.w, a1[q].w);
    }
  }

  const int j2 = tid >> 4;           // phase-2 agent slot (0..15)
  const int cp = tid & 15;           // phase-2 channel pair
  const int n_s = counts[s];

  for (int g0 = 0; g0 < n_s; g0 += GRP) {
    const int m = min(GRP, n_s - g0);
    __syncthreads();                 // prev alpha/a2l reads done (also guards
                                     // ubuf's Wl4 use on first iteration)
    {                                // stage a2l + aidl: 16 agents x 16 f4
      const int j = tid >> 4, e4 = tid & 15;
      if (j < m) {
        const int aj = lists[s * A_ + g0 + j];
        a2l[j][e4] = ((const float4*)att2)[aj * 16 + e4];
        if (e4 == 0) aidl[j] = aj;
      }
    }
    __syncthreads();

    // ---- phase 1: logits -> exp -> alpha_l ----
    for (int j = 0; j < m; ++j) {
      float c0 = 0.f, c1 = 0.f, c2 = 0.f, c3 = 0.f;
#pragma unroll
      for (int q = 0; q < 8; ++q) {
        const float4 t = a2l[j][eh * 8 + q];
        const float4 w = wf[q];
        const float4 av = a1[q];
        c0 = fmaf(fmaxf(av.x + t.x, 0.f), w.x, c0);
        c1 = fmaf(fmaxf(av.y + t.y, 0.f), w.y, c1);
        c2 = fmaf(fmaxf(av.z + t.z, 0.f), w.z, c2);
        c3 = fmaf(fmaxf(av.w + t.w, 0.f), w.w, c3);
      }
      float r = (c0 + c1) + (c2 + c3);
      r += __shfl_xor(r, 1);
      if (eh == 0) alpha_l[j][px] = __expf(r);
    }
    __syncthreads();

    // ---- phase 2: pool vs LDS gs chunk; channel pair per lane ----
    if (j2 < m) {
      const int a = aidl[j2];
      float2 s0 = make_float2(0.f, 0.f), s1 = make_float2(0.f, 0.f);
      float2 s2 = make_float2(0.f, 0.f), s3 = make_float2(0.f, 0.f);
      float  zs = 0.f;
#pragma unroll 4
      for (int p = 0; p < LPX; p += 4) {
        const float w0 = alpha_l[j2][p + 0];
        const float w1 = alpha_l[j2][p + 1];
        const float w2 = alpha_l[j2][p + 2];
        const float w3 = alpha_l[j2][p + 3];
        const float2 v0 = *(const float2*)&gsl[p + 0][cp * 2];
        const float2 v1 = *(const float2*)&gsl[p + 1][cp * 2];
        const float2 v2 = *(const float2*)&gsl[p + 2][cp * 2];
        const float2 v3 = *(const float2*)&gsl[p + 3][cp * 2];
        zs += (w0 + w1) + (w2 + w3);
        s0.x = fmaf(w0, v0.x, s0.x); s0.y = fmaf(w0, v0.y, s0.y);
        s1.x = fmaf(w1, v1.x, s1.x); s1.y = fmaf(w1, v1.y, s1.y);
        s2.x = fmaf(w2, v2.x, s2.x); s2.y = fmaf(w2, v2.y, s2.y);
        s3.x = fmaf(w3, v3.x, s3.x); s3.y = fmaf(w3, v3.y, s3.y);
      }
      const float2 acc = make_float2((s0.x + s1.x) + (s2.x + s3.x),
                                     (s0.y + s1.y) + (s2.y + s3.y));
      *(float2*)(partial + (long)ch * (A_ * C_) + (long)a * C_ + cp * 2) = acc;
      if (cp == 0) atomicAdd(&Z[a], zs);
    }
  }

  // ---- epilogue: last chunk-block of this scene normalizes it ----
  __syncthreads();                   // all stores of this block complete
  if (tid == 0) {
    __threadfence();                 // release: partials/Z visible device-wide
    lastFlag = (atomicAdd(&scene_done[s], 1) == NLCH - 1);
  }
  __syncthreads();
  if (lastFlag) {
    __threadfence();                 // acquire
    for (int i = tid; i < n_s * C_; i += 256) {
      const int j = i >> 5;          // agent slot in scene
      const int c = i & 31;
      const int a = lists[s * A_ + j];
      float sum = 0.f;
#pragma unroll
      for (int cc = 0; cc < NLCH; ++cc)
        sum += partial[(long)cc * (A_ * C_) + (long)a * C_ + c];
      out[(long)a * C_ + c] = sum / Z[a];
    }
  }
}

// ---------------------------------------------------------------------------
extern "C" void kernel_launch(void* const* d_in, const int* in_sizes, int n_in,
                              void* d_out, int out_size, void* d_ws, size_t ws_size,
                              hipStream_t stream) {
  const float* gs   = (const float*)d_in[0];  // [S,P,C]
  const int*   sidx = (const int*)  d_in[1];  // [A]
  const float* de   = (const float*)d_in[2];  // [A,D]
  const float* Wsn  = (const float*)d_in[3];  // [C,E]
  const float* bsn  = (const float*)d_in[4];  // [E]
  const float* Wdf  = (const float*)d_in[5];  // [D,E]
  const float* bdf  = (const float*)d_in[6];  // [E]
  const float* wfc  = (const float*)d_in[7];  // [E]
  // d_in[8] = b_fc: constant shift, cancels in softmax — unused.
  float* out = (float*)d_out;

  float* att2       = (float*)d_ws;                     // A*E      = 0.5 MB
  float* Z          = att2 + (long)A_ * E_;             // A floats
  int*   counts     = (int*)(Z + A_);                   // 64 ints
  int*   scene_done = counts + 64;                      // 64 ints
  int*   lists      = scene_done + 64;                  // S*A      = 0.5 MB
  float* partial    = (float*)(lists + (long)S_ * A_);  // NLCH*A*C = 4 MB

  prep_kernel <<<A_ / 16,   256, 0, stream>>>(de, Wdf, bdf, sidx, att2,
                                              counts, lists, Z, scene_done);
  fused_kernel<<<S_ * NLCH, 256, 0, stream>>>(gs, Wsn, bsn, wfc, att2,
                                              counts, lists, partial, Z,
                                              scene_done, out);
}

// Round 12
// 138.494 us; speedup vs baseline: 2.0857x; 2.0857x over previous
//
#include <hip/hip_runtime.h>

#define S_ 64
#define P_ 2048
#define C_ 32
#define A_ 2048
#define D_ 128
#define E_ 64

#define LPX  256             // pixels per fused block
#define NLCH (P_ / LPX)      // 8 chunks per scene
#define GRP  16              // agents per group
#define THR  512             // threads per fused block

// ---------------------------------------------------------------------------
// prep: att2[a,:] = de[a,:] @ W_df + b_df (128 blocks, 256 thr).
// Plus: atomic scene scatter (counts pre-zeroed by memset), block 0 zeros Z.
// ---------------------------------------------------------------------------
__global__ __launch_bounds__(256) void prep_kernel(
    const float* __restrict__ de, const float* __restrict__ Wdf,
    const float* __restrict__ bdf, const int* __restrict__ sidx,
    float* __restrict__ att2, int* __restrict__ counts,
    int* __restrict__ lists, float* __restrict__ Z) {
  __shared__ float4 Wl[128 * 16];
  __shared__ float4 bl[16];
  __shared__ float  dl[16 * 128];
  const int tid = threadIdx.x;

  if (blockIdx.x == 0) {
    for (int i = tid; i < A_; i += 256) Z[i] = 0.f;
  }
  // scatter this block's 16 agents
  if (tid < 16) {
    const int a = blockIdx.x * 16 + tid;
    const int s = sidx[a];
    const int pos = atomicAdd(&counts[s], 1);
    lists[s * A_ + pos] = a;
  }

  const float4* W4 = (const float4*)Wdf;
#pragma unroll
  for (int i = 0; i < 8; ++i) Wl[tid + i * 256] = W4[tid + i * 256];
  if (tid < 16) bl[tid] = ((const float4*)bdf)[tid];
  const long base = (long)blockIdx.x * (16 * 128);
#pragma unroll
  for (int i = 0; i < 8; ++i) dl[tid + i * 256] = de[base + tid + i * 256];
  __syncthreads();

  const int r = tid >> 4, e4 = tid & 15;
  float4 acc = bl[e4];
#pragma unroll 4
  for (int d = 0; d < 128; ++d) {
    const float  g = dl[r * 128 + d];
    const float4 w = Wl[d * 16 + e4];
    acc.x = fmaf(g, w.x, acc.x);
    acc.y = fmaf(g, w.y, acc.y);
    acc.z = fmaf(g, w.z, acc.z);
    acc.w = fmaf(g, w.w, acc.w);
  }
  ((float4*)att2)[((long)blockIdx.x * 16 + r) * 16 + e4] = acc;
}

// ---------------------------------------------------------------------------
// Fused logits + unnormalized exp + pooling. 512 threads, 256-px chunks.
// Block = (scene, chunk): 64*8 = 512 blocks -> 2 blocks/CU (LDS ~56 KB),
// 16 waves/CU. Phase 1 lane = (px = tid>>1, eh = tid&1): 32 e's per lane;
// exp needs no max subtraction (|logit| <~ 10 since |w_fc| <= 1/8).
// Phase 2 lane = (j2 = tid>>5, c = tid&31): one channel per lane.
// LDS: Wl4 unioned with alpha_l; gsl stride 34 (2-way max, free);
// alpha stride 260 (bank-distinct rows, broadcast reads).
// ---------------------------------------------------------------------------
__global__ __launch_bounds__(THR) void fused_kernel(
    const float* __restrict__ gs, const float* __restrict__ Wsn,
    const float* __restrict__ bsn, const float* __restrict__ wfc,
    const float* __restrict__ att2, const int* __restrict__ counts,
    const int* __restrict__ lists, float* __restrict__ partial,
    float* __restrict__ Z) {
  const int s   = blockIdx.x >> 3;
  const int ch  = blockIdx.x & (NLCH - 1);
  const int p0  = ch * LPX;
  const int tid = threadIdx.x;
  const int px  = tid >> 1;          // 0..255
  const int eh  = tid & 1;           // e-half (32 e's)

  __shared__ float  gsl[LPX][34];    // 34 KB
  __shared__ float  ubuf[GRP * 260]; // 16.6 KB: Wl4 (preamble) / alpha_l (loop)
  __shared__ float4 a2l[GRP][16];    // 4 KB
  __shared__ int    aidl[GRP];

  float4* Wl4 = (float4*)ubuf;                       // 512 float4 (8 KB) used
  float (*alpha_l)[260] = (float(*)[260])ubuf;

  // stage W_sn (512 float4)
  Wl4[tid] = ((const float4*)Wsn)[tid];

  // stage gs chunk: 256 px x 32 c = 2048 float4
  const float4* g4 = (const float4*)(gs + ((long)s * P_ + p0) * C_);
#pragma unroll
  for (int k = 0; k < 4; ++k) {
    const int f = tid + k * THR;
    const float4 v = g4[f];
    const int pp = f >> 3, c0 = (f & 7) * 4;
    gsl[pp][c0]     = v.x;
    gsl[pp][c0 + 1] = v.y;
    gsl[pp][c0 + 2] = v.z;
    gsl[pp][c0 + 3] = v.w;
  }

  // per-lane w_fc and bias-initialized att1 accumulator (32 e's each)
  const float4* wf4 = (const float4*)wfc;
  const float4* b4  = (const float4*)bsn;
  float4 wf[8], a1[8];
#pragma unroll
  for (int q = 0; q < 8; ++q) { wf[q] = wf4[eh * 8 + q]; a1[q] = b4[eh * 8 + q]; }
  __syncthreads();

  // att1 for (pixel px, this lane's 32 e's): last reads of Wl4 (= ubuf)
#pragma unroll
  for (int c = 0; c < 32; ++c) {
    const float g = gsl[px][c];
#pragma unroll
    for (int q = 0; q < 8; ++q) {
      const float4 w = Wl4[c * 16 + eh * 8 + q];
      a1[q].x = fmaf(g, w.x, a1[q].x);
      a1[q].y = fmaf(g, w.y, a1[q].y);
      a1[q].z = fmaf(g, w.z, a1[q].z);
      a1[q].w = fmaf(g, w.w, a1[q].w);
    }
  }

  const int j2 = tid >> 5;           // phase-2 agent slot (0..15)
  const int c2 = tid & 31;           // phase-2 channel
  const int n_s = counts[s];

  for (int g0 = 0; g0 < n_s; g0 += GRP) {
    const int m = min(GRP, n_s - g0);
    __syncthreads();                 // prev alpha/a2l reads done (also guards
                                     // ubuf's Wl4 use on first iteration)
    if (tid < GRP * 16) {            // stage a2l + aidl: 16 agents x 16 f4
      const int j = tid >> 4, e4 = tid & 15;
      if (j < m) {
        const int aj = lists[s * A_ + g0 + j];
        a2l[j][e4] = ((const float4*)att2)[aj * 16 + e4];
        if (e4 == 0) aidl[j] = aj;
      }
    }
    __syncthreads();

    // ---- phase 1: logits -> exp -> alpha_l ----
    for (int j = 0; j < m; ++j) {
      float c0 = 0.f, c1 = 0.f, c2s = 0.f, c3 = 0.f;
#pragma unroll
      for (int q = 0; q < 8; ++q) {
        const float4 t = a2l[j][eh * 8 + q];
        const float4 w = wf[q];
        const float4 av = a1[q];
        c0  = fmaf(fmaxf(av.x + t.x, 0.f), w.x, c0);
        c1  = fmaf(fmaxf(av.y + t.y, 0.f), w.y, c1);
        c2s = fmaf(fmaxf(av.z + t.z, 0.f), w.z, c2s);
        c3  = fmaf(fmaxf(av.w + t.w, 0.f), w.w, c3);
      }
      float r = (c0 + c1) + (c2s + c3);
      r += __shfl_xor(r, 1);
      if (eh == 0) alpha_l[j][px] = __expf(r);
    }
    __syncthreads();

    // ---- phase 2: pool vs LDS gs chunk; one channel per lane ----
    if (j2 < m) {
      const int a = aidl[j2];
      float s0 = 0.f, s1 = 0.f, s2 = 0.f, s3 = 0.f;
      float z0 = 0.f, z1 = 0.f, z2 = 0.f, z3 = 0.f;
#pragma unroll 2
      for (int p = 0; p < LPX; p += 4) {
        const float w0 = alpha_l[j2][p + 0];
        const float w1 = alpha_l[j2][p + 1];
        const float w2 = alpha_l[j2][p + 2];
        const float w3 = alpha_l[j2][p + 3];
        s0 = fmaf(w0, gsl[p + 0][c2], s0);
        s1 = fmaf(w1, gsl[p + 1][c2], s1);
        s2 = fmaf(w2, gsl[p + 2][c2], s2);
        s3 = fmaf(w3, gsl[p + 3][c2], s3);
        z0 += w0; z1 += w1; z2 += w2; z3 += w3;
      }
      partial[(long)ch * (A_ * C_) + (long)a * C_ + c2] =
          (s0 + s1) + (s2 + s3);
      if (c2 == 0) atomicAdd(&Z[a], (z0 + z1) + (z2 + z3));
    }
  }
}

// ---------------------------------------------------------------------------
// out[a,c] = (sum_ch partial[ch][a][c]) / Z[a]
// ---------------------------------------------------------------------------
__global__ __launch_bounds__(256) void norm_kernel(
    const float* __restrict__ partial, const float* __restrict__ Z,
    float* __restrict__ out) {
  const int i = blockIdx.x * 256 + threadIdx.x;   // a*C + c
  float sum = 0.f;
#pragma unroll
  for (int ch = 0; ch < NLCH; ++ch) sum += partial[(long)ch * (A_ * C_) + i];
  out[i] = sum / Z[i >> 5];
}

// ---------------------------------------------------------------------------
extern "C" void kernel_launch(void* const* d_in, const int* in_sizes, int n_in,
                              void* d_out, int out_size, void* d_ws, size_t ws_size,
                              hipStream_t stream) {
  const float* gs   = (const float*)d_in[0];  // [S,P,C]
  const int*   sidx = (const int*)  d_in[1];  // [A]
  const float* de   = (const float*)d_in[2];  // [A,D]
  const float* Wsn  = (const float*)d_in[3];  // [C,E]
  const float* bsn  = (const float*)d_in[4];  // [E]
  const float* Wdf  = (const float*)d_in[5];  // [D,E]
  const float* bdf  = (const float*)d_in[6];  // [E]
  const float* wfc  = (const float*)d_in[7];  // [E]
  // d_in[8] = b_fc: constant shift, cancels in softmax — unused.
  float* out = (float*)d_out;

  float* att2    = (float*)d_ws;                    // A*E      = 0.5 MB
  float* Z       = att2 + (long)A_ * E_;            // A floats
  int*   counts  = (int*)(Z + A_);                  // 64 ints
  int*   lists   = counts + 64;                     // S*A      = 0.5 MB
  float* partial = (float*)(lists + (long)S_ * A_); // NLCH*A*C = 2 MB

  hipMemsetAsync(counts, 0, 64 * sizeof(int), stream);
  prep_kernel <<<A_ / 16,   256, 0, stream>>>(de, Wdf, bdf, sidx, att2,
                                              counts, lists, Z);
  fused_kernel<<<S_ * NLCH, THR, 0, stream>>>(gs, Wsn, bsn, wfc, att2,
                                              counts, lists, partial, Z);
  norm_kernel <<<(A_ * C_) / 256, 256, 0, stream>>>(partial, Z, out);
}

// Round 13
// 133.621 us; speedup vs baseline: 2.1618x; 1.0365x over previous
//
#include <hip/hip_runtime.h>

#define S_ 64
#define P_ 2048
#define C_ 32
#define A_ 2048
#define D_ 128
#define E_ 64

#define LPX  256             // pixels per fused block
#define NLCH (P_ / LPX)      // 8 chunks per scene
#define GRP  16              // agents per group
#define THR  512             // threads per fused block

// ---------------------------------------------------------------------------
// prep: att2[a,:] = de[a,:] @ W_df + b_df (128 blocks, 256 thr).
// Plus: atomic scene scatter (counts pre-zeroed by memset), block 0 zeros Z.
// ---------------------------------------------------------------------------
__global__ __launch_bounds__(256) void prep_kernel(
    const float* __restrict__ de, const float* __restrict__ Wdf,
    const float* __restrict__ bdf, const int* __restrict__ sidx,
    float* __restrict__ att2, int* __restrict__ counts,
    int* __restrict__ lists, float* __restrict__ Z) {
  __shared__ float4 Wl[128 * 16];
  __shared__ float4 bl[16];
  __shared__ float  dl[16 * 128];
  const int tid = threadIdx.x;

  if (blockIdx.x == 0) {
    for (int i = tid; i < A_; i += 256) Z[i] = 0.f;
  }
  // scatter this block's 16 agents
  if (tid < 16) {
    const int a = blockIdx.x * 16 + tid;
    const int s = sidx[a];
    const int pos = atomicAdd(&counts[s], 1);
    lists[s * A_ + pos] = a;
  }

  const float4* W4 = (const float4*)Wdf;
#pragma unroll
  for (int i = 0; i < 8; ++i) Wl[tid + i * 256] = W4[tid + i * 256];
  if (tid < 16) bl[tid] = ((const float4*)bdf)[tid];
  const long base = (long)blockIdx.x * (16 * 128);
#pragma unroll
  for (int i = 0; i < 8; ++i) dl[tid + i * 256] = de[base + tid + i * 256];
  __syncthreads();

  const int r = tid >> 4, e4 = tid & 15;
  float4 acc = bl[e4];
#pragma unroll 4
  for (int d = 0; d < 128; ++d) {
    const float  g = dl[r * 128 + d];
    const float4 w = Wl[d * 16 + e4];
    acc.x = fmaf(g, w.x, acc.x);
    acc.y = fmaf(g, w.y, acc.y);
    acc.z = fmaf(g, w.z, acc.z);
    acc.w = fmaf(g, w.w, acc.w);
  }
  ((float4*)att2)[((long)blockIdx.x * 16 + r) * 16 + e4] = acc;
}

// ---------------------------------------------------------------------------
// Fused logits + unnormalized exp + pooling. 512 threads, 256-px chunks.
// Phase 1 lane = (px = tid>>1, eh = tid&1): 32 e's per lane; exp needs no
// max subtraction (|logit| <~ 10 since |w_fc| <= 1/8).
// Phase 2 lane = (j2 = tid>>5, pg = (tid>>3)&3, q8 = tid&7): each lane pools
// 4 channels (ONE ds_read_b128/4px, stride-36 rows -> balanced 4-lane/quad =
// data-rate floor) x 64 pixels (p = pg+4i) for one agent; alpha is a b32
// broadcast. Cross-pg reduce via shfl_xor(8/16); pg==0 lanes store coalesced
// float4 partials. R12 showed occupancy-insensitive ~60us with 8 scalar LDS
// reads per 4px -> LDS-issue-bound; this cuts phase-2 LDS inst 4x.
// ---------------------------------------------------------------------------
__global__ __launch_bounds__(THR) void fused_kernel(
    const float* __restrict__ gs, const float* __restrict__ Wsn,
    const float* __restrict__ bsn, const float* __restrict__ wfc,
    const float* __restrict__ att2, const int* __restrict__ counts,
    const int* __restrict__ lists, float* __restrict__ partial,
    float* __restrict__ Z) {
  const int s   = blockIdx.x >> 3;
  const int ch  = blockIdx.x & (NLCH - 1);
  const int p0  = ch * LPX;
  const int tid = threadIdx.x;
  const int px  = tid >> 1;          // 0..255
  const int eh  = tid & 1;           // e-half (32 e's)

  __shared__ float  gsl[LPX][36];    // 36.9 KB; 144 B rows (16B-aligned)
  __shared__ float  ubuf[GRP * 260]; // 16.6 KB: Wl4 (preamble) / alpha_l (loop)
  __shared__ float4 a2l[GRP][16];    // 4 KB
  __shared__ int    aidl[GRP];

  float4* Wl4 = (float4*)ubuf;                       // 512 float4 (8 KB) used
  float (*alpha_l)[260] = (float(*)[260])ubuf;

  // stage W_sn (512 float4)
  Wl4[tid] = ((const float4*)Wsn)[tid];

  // stage gs chunk: 256 px x 32 c = 2048 float4
  const float4* g4 = (const float4*)(gs + ((long)s * P_ + p0) * C_);
#pragma unroll
  for (int k = 0; k < 4; ++k) {
    const int f = tid + k * THR;
    const float4 v = g4[f];
    const int pp = f >> 3, c0 = (f & 7) * 4;
    gsl[pp][c0]     = v.x;
    gsl[pp][c0 + 1] = v.y;
    gsl[pp][c0 + 2] = v.z;
    gsl[pp][c0 + 3] = v.w;
  }

  // per-lane w_fc and bias-initialized att1 accumulator (32 e's each)
  const float4* wf4 = (const float4*)wfc;
  const float4* b4  = (const float4*)bsn;
  float4 wf[8], a1[8];
#pragma unroll
  for (int q = 0; q < 8; ++q) { wf[q] = wf4[eh * 8 + q]; a1[q] = b4[eh * 8 + q]; }
  __syncthreads();

  // att1 for (pixel px, this lane's 32 e's): last reads of Wl4 (= ubuf)
#pragma unroll
  for (int c = 0; c < 32; ++c) {
    const float g = gsl[px][c];
#pragma unroll
    for (int q = 0; q < 8; ++q) {
      const float4 w = Wl4[c * 16 + eh * 8 + q];
      a1[q].x = fmaf(g, w.x, a1[q].x);
      a1[q].y = fmaf(g, w.y, a1[q].y);
      a1[q].z = fmaf(g, w.z, a1[q].z);
      a1[q].w = fmaf(g, w.w, a1[q].w);
    }
  }

  const int j2 = tid >> 5;           // phase-2 agent slot (0..15)
  const int pg = (tid >> 3) & 3;     // phase-2 pixel phase (0..3)
  const int q8 = tid & 7;            // phase-2 channel quad (0..7)
  const int n_s = counts[s];

  for (int g0 = 0; g0 < n_s; g0 += GRP) {
    const int m = min(GRP, n_s - g0);
    __syncthreads();                 // prev alpha/a2l reads done (also guards
                                     // ubuf's Wl4 use on first iteration)
    if (tid < GRP * 16) {            // stage a2l + aidl: 16 agents x 16 f4
      const int j = tid >> 4, e4 = tid & 15;
      if (j < m) {
        const int aj = lists[s * A_ + g0 + j];
        a2l[j][e4] = ((const float4*)att2)[aj * 16 + e4];
        if (e4 == 0) aidl[j] = aj;
      }
    }
    __syncthreads();

    // ---- phase 1: logits -> exp -> alpha_l ----
    for (int j = 0; j < m; ++j) {
      float c0 = 0.f, c1 = 0.f, c2s = 0.f, c3 = 0.f;
#pragma unroll
      for (int q = 0; q < 8; ++q) {
        const float4 t = a2l[j][eh * 8 + q];
        const float4 w = wf[q];
        const float4 av = a1[q];
        c0  = fmaf(fmaxf(av.x + t.x, 0.f), w.x, c0);
        c1  = fmaf(fmaxf(av.y + t.y, 0.f), w.y, c1);
        c2s = fmaf(fmaxf(av.z + t.z, 0.f), w.z, c2s);
        c3  = fmaf(fmaxf(av.w + t.w, 0.f), w.w, c3);
      }
      float r = (c0 + c1) + (c2s + c3);
      r += __shfl_xor(r, 1);
      if (eh == 0) alpha_l[j][px] = __expf(r);
    }
    __syncthreads();

    // ---- phase 2: pool vs LDS gs chunk; b128 per 4 channels ----
    if (j2 < m) {
      const int a = aidl[j2];
      float4 acc0 = make_float4(0.f, 0.f, 0.f, 0.f);
      float4 acc1 = make_float4(0.f, 0.f, 0.f, 0.f);
      float  z0 = 0.f, z1 = 0.f;
#pragma unroll 8
      for (int i = 0; i < LPX / 4; i += 2) {
        const int pa = pg + 4 * i;
        const int pb = pg + 4 * (i + 1);
        const float w0 = alpha_l[j2][pa];
        const float w1 = alpha_l[j2][pb];
        const float4 v0 = *(const float4*)&gsl[pa][q8 * 4];
        const float4 v1 = *(const float4*)&gsl[pb][q8 * 4];
        z0 += w0; z1 += w1;
        acc0.x = fmaf(w0, v0.x, acc0.x); acc0.y = fmaf(w0, v0.y, acc0.y);
        acc0.z = fmaf(w0, v0.z, acc0.z); acc0.w = fmaf(w0, v0.w, acc0.w);
        acc1.x = fmaf(w1, v1.x, acc1.x); acc1.y = fmaf(w1, v1.y, acc1.y);
        acc1.z = fmaf(w1, v1.z, acc1.z); acc1.w = fmaf(w1, v1.w, acc1.w);
      }
      float4 acc = make_float4(acc0.x + acc1.x, acc0.y + acc1.y,
                               acc0.z + acc1.z, acc0.w + acc1.w);
      float z = z0 + z1;
      // reduce across the 4 pixel phases (lanes differ in tid bits 3-4)
      acc.x += __shfl_xor(acc.x, 8);  acc.y += __shfl_xor(acc.y, 8);
      acc.z += __shfl_xor(acc.z, 8);  acc.w += __shfl_xor(acc.w, 8);
      z     += __shfl_xor(z, 8);
      acc.x += __shfl_xor(acc.x, 16); acc.y += __shfl_xor(acc.y, 16);
      acc.z += __shfl_xor(acc.z, 16); acc.w += __shfl_xor(acc.w, 16);
      z     += __shfl_xor(z, 16);
      if (pg == 0) {
        *(float4*)(partial + (long)ch * (A_ * C_) + (long)a * C_ + q8 * 4) = acc;
        if (q8 == 0) atomicAdd(&Z[a], z);
      }
    }
  }
}

// ---------------------------------------------------------------------------
// out[a,c] = (sum_ch partial[ch][a][c]) / Z[a]
// ---------------------------------------------------------------------------
__global__ __launch_bounds__(256) void norm_kernel(
    const float* __restrict__ partial, const float* __restrict__ Z,
    float* __restrict__ out) {
  const int i = blockIdx.x * 256 + threadIdx.x;   // a*C + c
  float sum = 0.f;
#pragma unroll
  for (int ch = 0; ch < NLCH; ++ch) sum += partial[(long)ch * (A_ * C_) + i];
  out[i] = sum / Z[i >> 5];
}

// ---------------------------------------------------------------------------
extern "C" void kernel_launch(void* const* d_in, const int* in_sizes, int n_in,
                              void* d_out, int out_size, void* d_ws, size_t ws_size,
                              hipStream_t stream) {
  const float* gs   = (const float*)d_in[0];  // [S,P,C]
  const int*   sidx = (const int*)  d_in[1];  // [A]
  const float* de   = (const float*)d_in[2];  // [A,D]
  const float* Wsn  = (const float*)d_in[3];  // [C,E]
  const float* bsn  = (const float*)d_in[4];  // [E]
  const float* Wdf  = (const float*)d_in[5];  // [D,E]
  const float* bdf  = (const float*)d_in[6];  // [E]
  const float* wfc  = (const float*)d_in[7];  // [E]
  // d_in[8] = b_fc: constant shift, cancels in softmax — unused.
  float* out = (float*)d_out;

  float* att2    = (float*)d_ws;                    // A*E      = 0.5 MB
  float* Z       = att2 + (long)A_ * E_;            // A floats
  int*   counts  = (int*)(Z + A_);                  // 64 ints
  int*   lists   = counts + 64;                     // S*A      = 0.5 MB
  float* partial = (float*)(lists + (long)S_ * A_); // NLCH*A*C = 2 MB

  hipMemsetAsync(counts, 0, 64 * sizeof(int), stream);
  prep_kernel <<<A_ / 16,   256, 0, stream>>>(de, Wdf, bdf, sidx, att2,
                                              counts, lists, Z);
  fused_kernel<<<S_ * NLCH, THR, 0, stream>>>(gs, Wsn, bsn, wfc, att2,
                                              counts, lists, partial, Z);
  norm_kernel <<<(A_ * C_) / 256, 256, 0, stream>>>(partial, Z, out);
}